// Round 1
// baseline (567.798 us; speedup 1.0000x reference)
//
#include <hip/hip_runtime.h>
#include <hip/hip_bf16.h>
#include <stdint.h>

#define B_      8
#define GRID_   24
#define C_      768
#define NPATCH  (B_*GRID_*GRID_)   // 4608
#define PRE     1024
#define TGT     1024
#define NMEM    20000
#define NMEM_PAD 20096             // 157 * 128
#define IMG_    384
#define LIN1    (C_*9)             // 6912
#define SEQ     577                // GRID*GRID + 1

typedef __bf16 bf16_t;
typedef bf16_t bf16x8 __attribute__((ext_vector_type(8)));
typedef float  floatx4 __attribute__((ext_vector_type(4)));

// ---------------------------------------------------------------------------
// Kernel A: per-patch unfold -> MeanMapper pool (6912->1024, 3 layers)
//           -> Aggregator pool (3072->1024) -> emb (bf16) + ||e||^2 (fp32)
// One block per patch (4608 blocks, 256 threads).
// ---------------------------------------------------------------------------
__global__ __launch_bounds__(256) void emb_kernel(
    const float* __restrict__ f6, const float* __restrict__ f8,
    const float* __restrict__ f10,
    bf16_t* __restrict__ emb, float* __restrict__ enorm)
{
    __shared__ float u[LIN1];        // unfold vector, torch order j = c*9 + k
    __shared__ float pooled[3*PRE];  // concatenated per-layer pooled
    __shared__ float red[4];

    const int n   = blockIdx.x;
    const int b   = n / (GRID_*GRID_);
    const int yx  = n - b*(GRID_*GRID_);
    const int y   = yx / GRID_;
    const int x   = yx - y*GRID_;
    const int tid = threadIdx.x;

    const float* fl[3] = {f6, f8, f10};

#pragma unroll
    for (int l = 0; l < 3; ++l) {
        const float* f = fl[l];
        // stage 9 neighbor feature vectors into LDS in unfold order
        for (int idx = tid; idx < LIN1; idx += 256) {
            int k  = idx / C_;           // 0..8 neighbor (kh*3+kw)
            int c  = idx - k*C_;
            int kh = k / 3, kw = k - kh*3;
            int ny = y + kh - 1, nx = x + kw - 1;
            float v = 0.0f;
            if (ny >= 0 && ny < GRID_ && nx >= 0 && nx < GRID_)
                v = f[((size_t)b*SEQ + 1 + ny*GRID_ + nx)*C_ + c];
            u[c*9 + k] = v;              // stride-9 writes: gcd(9,32)=1, conflict-free
        }
        __syncthreads();
        // adaptive avg pool 6912 -> 1024 (windows of 7..8, overlapping)
#pragma unroll
        for (int t = 0; t < 4; ++t) {
            int i = tid + t*256;
            int s = (i * LIN1) >> 10;
            int e = ((i + 1) * LIN1 + 1023) >> 10;
            float sum = 0.0f;
            for (int j = s; j < e; ++j) sum += u[j];
            pooled[l*PRE + i] = sum / (float)(e - s);
        }
        __syncthreads();   // protect u before next layer overwrites
    }

    // Aggregator: exactly 3 contiguous taps per output (3072/1024 == 3)
    float psq = 0.0f;
#pragma unroll
    for (int t = 0; t < 4; ++t) {
        int i = tid + t*256;
        float v = (pooled[3*i] + pooled[3*i+1] + pooled[3*i+2]) * (1.0f/3.0f);
        emb[(size_t)n*TGT + i] = (bf16_t)v;
        psq += v*v;
    }
    // block-reduce ||e||^2
    for (int off = 32; off > 0; off >>= 1) psq += __shfl_down(psq, off, 64);
    if ((tid & 63) == 0) red[tid >> 6] = psq;
    __syncthreads();
    if (tid == 0) enorm[n] = (red[0] + red[1]) + (red[2] + red[3]);
}

// ---------------------------------------------------------------------------
// Kernel M: memory_bank fp32 -> bf16 (padded to 20096 rows) + ||m||^2
// One block per (padded) row.
// ---------------------------------------------------------------------------
__global__ __launch_bounds__(256) void mprep_kernel(
    const float* __restrict__ mb, bf16_t* __restrict__ mbf,
    float* __restrict__ mnorm)
{
    const int r   = blockIdx.x;
    const int tid = threadIdx.x;
    __shared__ float red[4];
    float psq = 0.0f;
    if (r < NMEM) {
#pragma unroll
        for (int t = 0; t < 4; ++t) {
            int c = tid + t*256;
            float v = mb[(size_t)r*TGT + c];
            mbf[(size_t)r*TGT + c] = (bf16_t)v;
            psq += v*v;
        }
    } else {
#pragma unroll
        for (int t = 0; t < 4; ++t)
            mbf[(size_t)r*TGT + tid + t*256] = (bf16_t)0.0f;
    }
    for (int off = 32; off > 0; off >>= 1) psq += __shfl_down(psq, off, 64);
    if ((tid & 63) == 0) red[tid >> 6] = psq;
    __syncthreads();
    if (tid == 0) mnorm[r] = (r < NMEM) ? ((red[0]+red[1])+(red[2]+red[3])) : 1e30f;
}

__global__ void init_kernel(int* __restrict__ p)
{
    int i = blockIdx.x*256 + threadIdx.x;
    if (i < NPATCH) p[i] = 0x7f7f7f7f;   // large positive float bits
}

// ---------------------------------------------------------------------------
// Kernel B: fused GEMM + min.  d2 = ||e||^2 + ||m||^2 - 2 e.m ; min over m.
// m97-style 128x128 tile, BK=32, 16x16x32 bf16 MFMA, global_load_lds width 16.
// grid (36 m-tiles, 157 n-tiles), 256 threads = 4 waves, each wave 64x64.
// ---------------------------------------------------------------------------
__device__ __forceinline__ void load_lds16(const void* g, void* l)
{
    __builtin_amdgcn_global_load_lds(
        (__attribute__((address_space(1))) void*)g,
        (__attribute__((address_space(3))) void*)l, 16, 0, 0);
}

__global__ __launch_bounds__(256) void nnmin_kernel(
    const bf16_t* __restrict__ E, const bf16_t* __restrict__ M,
    const float* __restrict__ enorm, const float* __restrict__ mnorm,
    int* __restrict__ out_min)
{
    __shared__ __attribute__((aligned(16))) bf16_t As[128*32];   // 8 KB
    __shared__ __attribute__((aligned(16))) bf16_t Bs[128*32];   // 8 KB

    const int m0   = blockIdx.x * 128;
    const int n0   = blockIdx.y * 128;
    const int tid  = threadIdx.x;
    const int wave = tid >> 6;
    const int lane = tid & 63;
    const int wm   = wave >> 1;        // 0..1 : 64-row half
    const int wn   = wave & 1;         // 0..1 : 64-col half

    // staging assignment: lane covers 8 contiguous bf16 (16 B)
    const int sr = lane >> 2;          // 0..15 row within 16-row chunk
    const int sc = (lane & 3) * 8;     // k offset 0/8/16/24

    const bf16_t* gA0 = E + (size_t)(m0 + wave*16 + sr)*TGT + sc;
    const bf16_t* gA1 = gA0 + (size_t)64*TGT;
    const bf16_t* gB0 = M + (size_t)(n0 + wave*16 + sr)*TGT + sc;
    const bf16_t* gB1 = gB0 + (size_t)64*TGT;
    bf16_t* lA0 = As + wave*512 + lane*8;
    bf16_t* lA1 = lA0 + 64*32;
    bf16_t* lB0 = Bs + wave*512 + lane*8;
    bf16_t* lB1 = lB0 + 64*32;

    floatx4 acc[4][4];
#pragma unroll
    for (int i = 0; i < 4; ++i)
#pragma unroll
        for (int j = 0; j < 4; ++j) acc[i][j] = (floatx4)0.0f;

    const int fr = lane & 15;          // fragment row (m or n within 16)
    const int fq = (lane >> 4) * 8;    // k offset of this quad

    for (int k0 = 0; k0 < TGT; k0 += 32) {
        load_lds16(gA0 + k0, lA0);
        load_lds16(gA1 + k0, lA1);
        load_lds16(gB0 + k0, lB0);
        load_lds16(gB1 + k0, lB1);
        __syncthreads();               // drains vmcnt: tiles visible

        bf16x8 a[4], b[4];
#pragma unroll
        for (int t = 0; t < 4; ++t)
            a[t] = *(const bf16x8*)(As + (wm*64 + t*16 + fr)*32 + fq);
#pragma unroll
        for (int t = 0; t < 4; ++t)
            b[t] = *(const bf16x8*)(Bs + (wn*64 + t*16 + fr)*32 + fq);
#pragma unroll
        for (int tm = 0; tm < 4; ++tm)
#pragma unroll
            for (int tn = 0; tn < 4; ++tn)
                acc[tm][tn] = __builtin_amdgcn_mfma_f32_16x16x32_bf16(
                    a[tm], b[tn], acc[tm][tn], 0, 0, 0);
        __syncthreads();               // compute done before next overwrite
    }

    // epilogue: d2 + min over this block's 128 columns, atomicMin per row
    const int col  = lane & 15;        // C/D col = lane&15
    const int rowq = (lane >> 4) * 4;  // C/D row = quad*4 + reg
    const int colbase = n0 + wn*64;
#pragma unroll
    for (int tm = 0; tm < 4; ++tm) {
#pragma unroll
        for (int r = 0; r < 4; ++r) {
            int row = m0 + wm*64 + tm*16 + rowq + r;
            float en = enorm[row];
            float best = 1e38f;
#pragma unroll
            for (int tn = 0; tn < 4; ++tn) {
                float d2 = en + mnorm[colbase + tn*16 + col]
                         - 2.0f * acc[tm][tn][r];
                best = fminf(best, d2);
            }
            // min across the 16 lanes of this quad (they hold the 16 cols)
#pragma unroll
            for (int off = 1; off < 16; off <<= 1)
                best = fminf(best, __shfl_xor(best, off, 64));
            if (col == 0)
                atomicMin(&out_min[row], __float_as_int(best));
        }
    }
}

// ---------------------------------------------------------------------------
// Kernel C1: image scores = max over 576 patches per batch
// ---------------------------------------------------------------------------
__global__ __launch_bounds__(256) void score_kernel(
    const int* __restrict__ ps_bits, float* __restrict__ out)
{
    const int b = blockIdx.x, tid = threadIdx.x;
    __shared__ float red[4];
    float m = -1e38f;
    for (int i = tid; i < GRID_*GRID_; i += 256)
        m = fmaxf(m, __int_as_float(ps_bits[b*GRID_*GRID_ + i]));
    for (int off = 32; off > 0; off >>= 1) m = fmaxf(m, __shfl_down(m, off, 64));
    if ((tid & 63) == 0) red[tid >> 6] = m;
    __syncthreads();
    if (tid == 0) out[b] = fmaxf(fmaxf(red[0], red[1]), fmaxf(red[2], red[3]));
}

// ---------------------------------------------------------------------------
// Kernel C2: bilinear 24x24 -> 384x384 (jax half-pixel == clamped bilinear)
// ---------------------------------------------------------------------------
__global__ __launch_bounds__(256) void mask_kernel(
    const int* __restrict__ ps_bits, float* __restrict__ masks)
{
    int idx = blockIdx.x*256 + threadIdx.x;          // < 8*384*384
    int b  = idx / (IMG_*IMG_);
    int p  = idx - b*(IMG_*IMG_);
    int oy = p / IMG_, ox = p - oy*IMG_;

    float fy = (oy + 0.5f) * (1.0f/16.0f) - 0.5f;
    float fx = (ox + 0.5f) * (1.0f/16.0f) - 0.5f;
    int y0 = (int)floorf(fy); float ty = fy - (float)y0;
    int x0 = (int)floorf(fx); float tx = fx - (float)x0;
    int y0c = min(max(y0, 0), GRID_-1), y1c = min(max(y0+1, 0), GRID_-1);
    int x0c = min(max(x0, 0), GRID_-1), x1c = min(max(x0+1, 0), GRID_-1);

    const int* psb = ps_bits + b*GRID_*GRID_;
    float v00 = __int_as_float(psb[y0c*GRID_ + x0c]);
    float v01 = __int_as_float(psb[y0c*GRID_ + x1c]);
    float v10 = __int_as_float(psb[y1c*GRID_ + x0c]);
    float v11 = __int_as_float(psb[y1c*GRID_ + x1c]);
    float v0 = v00 + (v01 - v00)*tx;
    float v1 = v10 + (v11 - v10)*tx;
    masks[idx] = v0 + (v1 - v0)*ty;
}

// ---------------------------------------------------------------------------
extern "C" void kernel_launch(void* const* d_in, const int* in_sizes, int n_in,
                              void* d_out, int out_size, void* d_ws, size_t ws_size,
                              hipStream_t stream)
{
    const float* f6  = (const float*)d_in[0];
    const float* f8  = (const float*)d_in[1];
    const float* f10 = (const float*)d_in[2];
    const float* mb  = (const float*)d_in[3];
    float* out = (float*)d_out;

    char* ws = (char*)d_ws;
    bf16_t* emb  = (bf16_t*)ws;  ws += (size_t)NPATCH*TGT*sizeof(bf16_t);
    bf16_t* mbf  = (bf16_t*)ws;  ws += (size_t)NMEM_PAD*TGT*sizeof(bf16_t);
    float* enorm = (float*)ws;   ws += (size_t)NPATCH*sizeof(float);
    float* mnorm = (float*)ws;   ws += (size_t)NMEM_PAD*sizeof(float);
    int* psbits  = (int*)ws;     ws += (size_t)NPATCH*sizeof(int);

    hipLaunchKernelGGL(emb_kernel, dim3(NPATCH), dim3(256), 0, stream,
                       f6, f8, f10, emb, enorm);
    hipLaunchKernelGGL(mprep_kernel, dim3(NMEM_PAD), dim3(256), 0, stream,
                       mb, mbf, mnorm);
    hipLaunchKernelGGL(init_kernel, dim3((NPATCH+255)/256), dim3(256), 0, stream,
                       psbits);
    hipLaunchKernelGGL(nnmin_kernel, dim3(NPATCH/128, NMEM_PAD/128), dim3(256),
                       0, stream, emb, mbf, enorm, mnorm, psbits);
    hipLaunchKernelGGL(score_kernel, dim3(B_), dim3(256), 0, stream,
                       psbits, out);
    hipLaunchKernelGGL(mask_kernel, dim3((B_*IMG_*IMG_)/256), dim3(256), 0, stream,
                       psbits, out + B_);
}

// Round 2
// 443.739 us; speedup vs baseline: 1.2796x; 1.2796x over previous
//
#include <hip/hip_runtime.h>
#include <hip/hip_bf16.h>
#include <stdint.h>

#define B_      8
#define GRID_   24
#define C_      768
#define NPATCH  (B_*GRID_*GRID_)   // 4608
#define PRE     1024
#define TGT     1024
#define NMEM    20000
#define NMEM_PAD 20096             // 157 * 128
#define IMG_    384
#define SEQ     577                // GRID*GRID + 1

typedef __bf16 bf16_t;
typedef bf16_t bf16x8 __attribute__((ext_vector_type(8)));
typedef bf16_t bf16x4 __attribute__((ext_vector_type(4)));
typedef float  floatx4 __attribute__((ext_vector_type(4)));

// ---------------------------------------------------------------------------
// Kernel A: per-patch pooled embedding, register-direct.
// 6912/1024 = 27/4: output group q (4 outputs) touches channels 3q..3q+2
// across all 9 unfold neighbors with fixed tap patterns:
//   r=0: c0 k0-6 (/7)   r=1: c0 k6-8 + c1 k0-4 (/8)
//   r=2: c1 k4-8 + c2 k0-2 (/8)   r=3: c2 k2-8 (/7)
// Thread t = group q. No unfold LDS, no index division.
// ---------------------------------------------------------------------------
__global__ __launch_bounds__(256) void emb_kernel(
    const float* __restrict__ f6, const float* __restrict__ f8,
    const float* __restrict__ f10,
    bf16_t* __restrict__ emb, float* __restrict__ enorm)
{
    __shared__ float pooled[3*PRE];   // 12 KB
    __shared__ float red[4];

    const int n   = blockIdx.x;
    const int b   = n / (GRID_*GRID_);
    const int yx  = n - b*(GRID_*GRID_);
    const int y   = yx / GRID_;
    const int x   = yx - y*GRID_;
    const int t   = threadIdx.x;

    const float* fl[3] = {f6, f8, f10};

#pragma unroll
    for (int l = 0; l < 3; ++l) {
        const float* f = fl[l];
        float A0 = 0.f, B0 = 0.f, C1 = 0.f, D1 = 0.f, E2 = 0.f, F2 = 0.f;
#pragma unroll
        for (int k = 0; k < 9; ++k) {
            const int kh = k / 3, kw = k - kh*3;
            const int ny = y + kh - 1, nx = x + kw - 1;
            const bool v = (ny >= 0 && ny < GRID_ && nx >= 0 && nx < GRID_);
            // block-uniform validity: clamp offset so loads are always safe
            const int off = v ? (b*SEQ + 1 + ny*GRID_ + nx) : (b*SEQ);
            const float* p = f + (size_t)off*C_ + 3*t;
            float a = p[0], bq = p[1], c = p[2];
            if (!v) { a = 0.f; bq = 0.f; c = 0.f; }   // uniform select
            if (k <= 6) A0 += a;
            if (k >= 6) B0 += a;
            if (k <= 4) C1 += bq;
            if (k >= 4) D1 += bq;
            if (k <= 2) E2 += c;
            if (k >= 2) F2 += c;
        }
        float4 pv;
        pv.x = A0 * (1.f/7.f);
        pv.y = (B0 + C1) * (1.f/8.f);
        pv.z = (D1 + E2) * (1.f/8.f);
        pv.w = F2 * (1.f/7.f);
        *(float4*)(pooled + l*PRE + 4*t) = pv;   // stride-16B: conflict-free
    }
    __syncthreads();

    // Aggregator: out j = mean of pooled[3j..3j+2] (concatenated across layers)
    float psq = 0.f;
    bf16x4 ev;
#pragma unroll
    for (int r = 0; r < 4; ++r) {
        const int j = 4*t + r;
        float vv = (pooled[3*j] + pooled[3*j+1] + pooled[3*j+2]) * (1.f/3.f);
        ev[r] = (bf16_t)vv;
        psq += vv*vv;
    }
    *(bf16x4*)(emb + (size_t)n*TGT + 4*t) = ev;

    for (int off = 32; off > 0; off >>= 1) psq += __shfl_down(psq, off, 64);
    if ((t & 63) == 0) red[t >> 6] = psq;
    __syncthreads();
    if (t == 0) enorm[n] = (red[0] + red[1]) + (red[2] + red[3]);
}

// ---------------------------------------------------------------------------
// Kernel M: memory_bank fp32 -> bf16 (padded rows zeroed) + ||m||^2, float4.
// ---------------------------------------------------------------------------
__global__ __launch_bounds__(256) void mprep_kernel(
    const float* __restrict__ mb, bf16_t* __restrict__ mbf,
    float* __restrict__ mnorm)
{
    const int r = blockIdx.x;
    const int t = threadIdx.x;
    __shared__ float red[4];
    float psq = 0.f;
    if (r < NMEM) {
        float4 v = ((const float4*)(mb + (size_t)r*TGT))[t];
        bf16x4 o;
        o[0] = (bf16_t)v.x; o[1] = (bf16_t)v.y;
        o[2] = (bf16_t)v.z; o[3] = (bf16_t)v.w;
        ((bf16x4*)(mbf + (size_t)r*TGT))[t] = o;
        psq = v.x*v.x + v.y*v.y + v.z*v.z + v.w*v.w;
    } else {
        bf16x4 z; z[0] = z[1] = z[2] = z[3] = (bf16_t)0.f;
        ((bf16x4*)(mbf + (size_t)r*TGT))[t] = z;
    }
    for (int off = 32; off > 0; off >>= 1) psq += __shfl_down(psq, off, 64);
    if ((t & 63) == 0) red[t >> 6] = psq;
    __syncthreads();
    if (t == 0) mnorm[r] = (r < NMEM) ? ((red[0]+red[1])+(red[2]+red[3])) : 1e30f;
}

__global__ void init_kernel(int* __restrict__ p)
{
    int i = blockIdx.x*256 + threadIdx.x;
    if (i < NPATCH) p[i] = 0x7f7f7f7f;   // ~3.4e38 as float bits
}

// ---------------------------------------------------------------------------
// Kernel B: fused GEMM + min with XOR-swizzled LDS.
// LDS slot s of chunk-row r holds global k-group  g = s ^ ((r>>1)&3).
// Swizzle is applied on the *global* side of global_load_lds (per-lane addr),
// un-applied at fragment read. Rows 0-7 of a quad then cover all 32 banks
// exactly once -> ds_read_b128 conflicts drop from 8-way to free 2-way.
// ---------------------------------------------------------------------------
__device__ __forceinline__ void load_lds16(const void* g, void* l)
{
    __builtin_amdgcn_global_load_lds(
        (__attribute__((address_space(1))) void*)g,
        (__attribute__((address_space(3))) void*)l, 16, 0, 0);
}

__global__ __launch_bounds__(256) void nnmin_kernel(
    const bf16_t* __restrict__ E, const bf16_t* __restrict__ M,
    const float* __restrict__ enorm, const float* __restrict__ mnorm,
    int* __restrict__ out_min)
{
    __shared__ __attribute__((aligned(16))) bf16_t As[128*32];   // 8 KB
    __shared__ __attribute__((aligned(16))) bf16_t Bs[128*32];   // 8 KB

    const int m0   = blockIdx.x * 128;
    const int n0   = blockIdx.y * 128;
    const int tid  = threadIdx.x;
    const int wave = tid >> 6;
    const int lane = tid & 63;
    const int wm   = wave >> 1;
    const int wn   = wave & 1;

    // staging: lane -> (chunk row sr, LDS slot), fetches swizzled k-group kg
    const int sr   = lane >> 2;                 // 0..15
    const int slot = lane & 3;                  // LDS 16B slot in row
    const int kg   = slot ^ ((sr >> 1) & 3);    // global k-group fetched

    const bf16_t* gA0 = E + (size_t)(m0 + wave*16 + sr)*TGT + kg*8;
    const bf16_t* gA1 = gA0 + (size_t)64*TGT;
    const bf16_t* gB0 = M + (size_t)(n0 + wave*16 + sr)*TGT + kg*8;
    const bf16_t* gB1 = gB0 + (size_t)64*TGT;
    bf16_t* lA0 = As + wave*512 + lane*8;
    bf16_t* lA1 = lA0 + 64*32;
    bf16_t* lB0 = Bs + wave*512 + lane*8;
    bf16_t* lB1 = lB0 + 64*32;

    floatx4 acc[4][4];
#pragma unroll
    for (int i = 0; i < 4; ++i)
#pragma unroll
        for (int j = 0; j < 4; ++j) acc[i][j] = (floatx4)0.0f;

    const int fr = lane & 15;                   // fragment row
    const int fg = lane >> 4;                   // k-group wanted (quad)
    const int sg = fg ^ ((fr >> 1) & 3);        // swizzled LDS slot

    for (int k0 = 0; k0 < TGT; k0 += 32) {
        load_lds16(gA0 + k0, lA0);
        load_lds16(gA1 + k0, lA1);
        load_lds16(gB0 + k0, lB0);
        load_lds16(gB1 + k0, lB1);
        __syncthreads();

        bf16x8 a[4], b[4];
#pragma unroll
        for (int t = 0; t < 4; ++t)
            a[t] = *(const bf16x8*)(As + (wm*64 + t*16 + fr)*32 + sg*8);
#pragma unroll
        for (int t = 0; t < 4; ++t)
            b[t] = *(const bf16x8*)(Bs + (wn*64 + t*16 + fr)*32 + sg*8);
#pragma unroll
        for (int tm = 0; tm < 4; ++tm)
#pragma unroll
            for (int tn = 0; tn < 4; ++tn)
                acc[tm][tn] = __builtin_amdgcn_mfma_f32_16x16x32_bf16(
                    a[tm], b[tn], acc[tm][tn], 0, 0, 0);
        __syncthreads();
    }

    // epilogue: d2 + min over this block's 128 columns, atomicMin per row
    const int col  = lane & 15;
    const int rowq = (lane >> 4) * 4;
    const int colbase = n0 + wn*64;
#pragma unroll
    for (int tm = 0; tm < 4; ++tm) {
#pragma unroll
        for (int r = 0; r < 4; ++r) {
            int row = m0 + wm*64 + tm*16 + rowq + r;
            float en = enorm[row];
            float best = 1e38f;
#pragma unroll
            for (int tn = 0; tn < 4; ++tn) {
                float d2 = en + mnorm[colbase + tn*16 + col]
                         - 2.0f * acc[tm][tn][r];
                best = fminf(best, d2);
            }
#pragma unroll
            for (int off = 1; off < 16; off <<= 1)
                best = fminf(best, __shfl_xor(best, off, 64));
            if (col == 0)
                atomicMin(&out_min[row], __float_as_int(best));
        }
    }
}

// ---------------------------------------------------------------------------
// Kernel C1: image scores = max over 576 patches per batch
// ---------------------------------------------------------------------------
__global__ __launch_bounds__(256) void score_kernel(
    const int* __restrict__ ps_bits, float* __restrict__ out)
{
    const int b = blockIdx.x, tid = threadIdx.x;
    __shared__ float red[4];
    float m = -1e38f;
    for (int i = tid; i < GRID_*GRID_; i += 256)
        m = fmaxf(m, __int_as_float(ps_bits[b*GRID_*GRID_ + i]));
    for (int off = 32; off > 0; off >>= 1) m = fmaxf(m, __shfl_down(m, off, 64));
    if ((tid & 63) == 0) red[tid >> 6] = m;
    __syncthreads();
    if (tid == 0) out[b] = fmaxf(fmaxf(red[0], red[1]), fmaxf(red[2], red[3]));
}

// ---------------------------------------------------------------------------
// Kernel C2: bilinear 24x24 -> 384x384 (jax half-pixel == clamped bilinear)
// ---------------------------------------------------------------------------
__global__ __launch_bounds__(256) void mask_kernel(
    const int* __restrict__ ps_bits, float* __restrict__ masks)
{
    int idx = blockIdx.x*256 + threadIdx.x;
    int b  = idx / (IMG_*IMG_);
    int p  = idx - b*(IMG_*IMG_);
    int oy = p / IMG_, ox = p - oy*IMG_;

    float fy = (oy + 0.5f) * (1.0f/16.0f) - 0.5f;
    float fx = (ox + 0.5f) * (1.0f/16.0f) - 0.5f;
    int y0 = (int)floorf(fy); float ty = fy - (float)y0;
    int x0 = (int)floorf(fx); float tx = fx - (float)x0;
    int y0c = min(max(y0, 0), GRID_-1), y1c = min(max(y0+1, 0), GRID_-1);
    int x0c = min(max(x0, 0), GRID_-1), x1c = min(max(x0+1, 0), GRID_-1);

    const int* psb = ps_bits + b*GRID_*GRID_;
    float v00 = __int_as_float(psb[y0c*GRID_ + x0c]);
    float v01 = __int_as_float(psb[y0c*GRID_ + x1c]);
    float v10 = __int_as_float(psb[y1c*GRID_ + x0c]);
    float v11 = __int_as_float(psb[y1c*GRID_ + x1c]);
    float v0 = v00 + (v01 - v00)*tx;
    float v1 = v10 + (v11 - v10)*tx;
    masks[idx] = v0 + (v1 - v0)*ty;
}

// ---------------------------------------------------------------------------
extern "C" void kernel_launch(void* const* d_in, const int* in_sizes, int n_in,
                              void* d_out, int out_size, void* d_ws, size_t ws_size,
                              hipStream_t stream)
{
    const float* f6  = (const float*)d_in[0];
    const float* f8  = (const float*)d_in[1];
    const float* f10 = (const float*)d_in[2];
    const float* mb  = (const float*)d_in[3];
    float* out = (float*)d_out;

    char* ws = (char*)d_ws;
    bf16_t* emb  = (bf16_t*)ws;  ws += (size_t)NPATCH*TGT*sizeof(bf16_t);
    bf16_t* mbf  = (bf16_t*)ws;  ws += (size_t)NMEM_PAD*TGT*sizeof(bf16_t);
    float* enorm = (float*)ws;   ws += (size_t)NPATCH*sizeof(float);
    float* mnorm = (float*)ws;   ws += (size_t)NMEM_PAD*sizeof(float);
    int* psbits  = (int*)ws;     ws += (size_t)NPATCH*sizeof(int);

    hipLaunchKernelGGL(emb_kernel, dim3(NPATCH), dim3(256), 0, stream,
                       f6, f8, f10, emb, enorm);
    hipLaunchKernelGGL(mprep_kernel, dim3(NMEM_PAD), dim3(256), 0, stream,
                       mb, mbf, mnorm);
    hipLaunchKernelGGL(init_kernel, dim3((NPATCH+255)/256), dim3(256), 0, stream,
                       psbits);
    hipLaunchKernelGGL(nnmin_kernel, dim3(NPATCH/128, NMEM_PAD/128), dim3(256),
                       0, stream, emb, mbf, enorm, mnorm, psbits);
    hipLaunchKernelGGL(score_kernel, dim3(B_), dim3(256), 0, stream,
                       psbits, out);
    hipLaunchKernelGGL(mask_kernel, dim3((B_*IMG_*IMG_)/256), dim3(256), 0, stream,
                       psbits, out + B_);
}